// Round 9
// baseline (399.457 us; speedup 1.0000x reference)
//
#include <hip/hip_runtime.h>

#define NEG_SLOPE 0.2f
#define LOG2E 1.44269504088896340736f

typedef unsigned short ushort_t;
typedef unsigned int uint_t;
typedef __attribute__((ext_vector_type(8))) short bf16x8;   // 8 bf16 in 4 VGPRs
typedef __attribute__((ext_vector_type(4))) float f32x4;
typedef __attribute__((ext_vector_type(2))) float f32x2;    // maps to v_pk_*_f32 on gfx950

__device__ inline float bf2f(ushort_t u) { union { uint_t i; float f; } v; v.i = ((uint_t)u) << 16; return v.f; }
__device__ inline ushort_t f2bf(float f) {
    union { float f; uint_t u; } v; v.f = f;
    uint_t r = v.u + 0x7fffu + ((v.u >> 16) & 1u);
    return (ushort_t)(r >> 16);
}
// unpack 2 packed bf16 -> f32x2 (exact: shl + and)
__device__ inline f32x2 up2v(uint_t w) {
    union { uint_t i; float f; } lo, hi;
    lo.i = w << 16; hi.i = w & 0xFFFF0000u;
    return (f32x2){lo.f, hi.f};
}
// fast unpack: hi word used unmasked (adds <=0.5 ulp-of-bf16 mantissa noise; saves the AND)
__device__ inline f32x2 up2f(uint_t w) {
    union { uint_t i; float f; } lo, hi;
    lo.i = w << 16; hi.i = w;
    return (f32x2){lo.f, hi.f};
}
// dtype-flexible loads (bf=1: buffer holds bf16; bf=0: fp32)
__device__ inline float ld_f(const void* p, size_t i, int bf) { return bf ? bf2f(((const ushort_t*)p)[i]) : ((const float*)p)[i]; }
__device__ inline ushort_t ld_b(const void* p, size_t i, int bf) { return bf ? ((const ushort_t*)p)[i] : f2bf(((const float*)p)[i]); }
// edge fetch with int64/int32 handling; self-loops appended at e >= E_in
__device__ inline void edge_sd(const int* __restrict__ ei, int e, int E_in, int i64, int& src, int& dst) {
    if (e < E_in) {
        if (i64) { src = ei[2 * (size_t)e]; dst = ei[2 * ((size_t)E_in + e)]; }
        else     { src = ei[e];             dst = ei[(size_t)E_in + e]; }
    } else { src = dst = e - E_in; }
}

// butterfly add via DPP (pure VALU, no DS pipe). 0xB1=xor1, 0x4E=xor2,
// 0x141=row_half_mirror (==xor4 once quads uniform), 0x140=row_mirror (==xor8 once
// 8-groups uniform). All stay within a 16-lane DPP row.
template <int CTRL>
__device__ inline float dpp_add(float v) {
    union { float f; int i; } u, r;
    u.f = v;
    r.i = __builtin_amdgcn_update_dpp(0, u.i, CTRL, 0xF, 0xF, true);
    return v + r.f;
}

// 16B gather with uniform base + 32-bit byte offset (SADDR form, no 64-bit VALU adds)
__device__ inline uint4 ldu4(const ushort_t* __restrict__ base, uint_t boff) {
    return *(const uint4*)((const char*)base + (size_t)boff);
}

// ---------------- dtype detection ----------------
__global__ void k_detect(const uint_t* __restrict__ xw, const int* __restrict__ ei, int* flags) {
    __shared__ int cnt;
    if (threadIdx.x == 0) cnt = 0;
    __syncthreads();
    uint_t w = xw[threadIdx.x];
    int eb = (int)((w >> 7) & 0xFFu);
    if (eb >= 113 && eb <= 142) atomicAdd(&cnt, 1);
    __syncthreads();
    if (threadIdx.x == 0) {
        flags[0] = (cnt > 128) ? 1 : 0;
        int z = 0;
        #pragma unroll
        for (int i = 1; i < 16; i += 2) z += (ei[i] == 0) ? 1 : 0;
        flags[1] = (z == 8) ? 1 : 0;
    }
}

// ------ fused front-end: degree count | cvt x->bf16 (fp32 input ONLY) | build WT | params ------
// When input is already bf16 the x->xb copy is skipped entirely (gemm reads x directly).
__global__ __launch_bounds__(256) void k_prep(const void* __restrict__ x, const void* Wl1, const void* Wr1,
                      const void* att1, const void* b1, const void* Wl2, const void* Wr2,
                      const void* att2, const void* b2, const void* Wo, const void* bo,
                      const int* __restrict__ ei, int E_in, int Etot, int* deg, ushort_t* xb,
                      ushort_t* WTl1, ushort_t* WTr1, ushort_t* WTl2, ushort_t* WTr2,
                      float* att1f, float* b1f, float* att2f, float* b2f, float* Wof, float* bof,
                      int N, int sW1, int sW2, int satt1, int sb1, int satt2, int sb2, int sWo, int sbo,
                      const int* flags) {
    int bf = flags[0];
    long r = (long)blockIdx.x * 256 + threadIdx.x;
    if (r < Etot) {   // degree count
        int e = (int)r, dst;
        if (e < E_in) dst = flags[1] ? ei[2 * ((size_t)E_in + e)] : ei[(size_t)E_in + e];
        else          dst = e - E_in;
        atomicAdd(&deg[dst], 1);
        return;
    }
    r -= Etot;
    long nx8 = (long)N * 16;    // 8-element chunks of x
    if (r < nx8) {
        if (!bf) {              // bf16 input: no copy needed, gemm reads x in place
            size_t base = (size_t)r * 8;
            const float* xf = (const float*)x + base;
            float4 a = *(const float4*)xf;
            float4 c = *(const float4*)(xf + 4);
            uint_t pk[4];
            pk[0] = (uint_t)f2bf(a.x) | ((uint_t)f2bf(a.y) << 16);
            pk[1] = (uint_t)f2bf(a.z) | ((uint_t)f2bf(a.w) << 16);
            pk[2] = (uint_t)f2bf(c.x) | ((uint_t)f2bf(c.y) << 16);
            pk[3] = (uint_t)f2bf(c.z) | ((uint_t)f2bf(c.w) << 16);
            *(uint4*)(xb + base) = make_uint4(pk[0], pk[1], pk[2], pk[3]);
        }
        return;
    }
    r -= nx8;
    if (r < sW1) { int n = r >> 7, k = r & 127; WTl1[r] = ld_b(Wl1, (size_t)k * 128 + n, bf); return; } r -= sW1;
    if (r < sW1) { int n = r >> 7, k = r & 127; WTr1[r] = ld_b(Wr1, (size_t)k * 128 + n, bf); return; } r -= sW1;
    if (r < sW2) { int n = r >> 7, k = r & 127; WTl2[r] = ld_b(Wl2, (size_t)k * 512 + n, bf); return; } r -= sW2;
    if (r < sW2) { int n = r >> 7, k = r & 127; WTr2[r] = ld_b(Wr2, (size_t)k * 512 + n, bf); return; } r -= sW2;
    if (r < satt1) { att1f[r] = ld_f(att1, r, bf); return; } r -= satt1;
    if (r < sb1)   { b1f[r]   = ld_f(b1, r, bf);   return; } r -= sb1;
    if (r < satt2) { att2f[r] = ld_f(att2, r, bf); return; } r -= satt2;
    if (r < sb2)   { b2f[r]   = ld_f(b2, r, bf);   return; } r -= sb2;
    if (r < sWo)   { Wof[r]   = ld_f(Wo, r, bf);   return; } r -= sWo;
    if (r < sbo)   { bof[r]   = ld_f(bo, r, bf);   return; }
}

// -------- hierarchical exclusive scan --------
__global__ __launch_bounds__(256) void k_scanA(const int* __restrict__ deg, int* offs, int* bsum, int n) {
    __shared__ int sh[256];
    int t = threadIdx.x;
    int i = blockIdx.x * 256 + t;
    int v = (i < n) ? deg[i] : 0;
    sh[t] = v; __syncthreads();
    #pragma unroll
    for (int off = 1; off < 256; off <<= 1) {
        int u = (t >= off) ? sh[t - off] : 0;
        __syncthreads();
        sh[t] += u; __syncthreads();
    }
    if (i < n) offs[i] = sh[t] - v;
    if (t == 255) bsum[blockIdx.x] = sh[255];
}

__global__ __launch_bounds__(256) void k_scanBC(int* offs, int* cursor, const int* __restrict__ bsum,
                                                int nb, int n) {
    __shared__ int sh[256];
    int t = threadIdx.x;
    int v = (t < nb) ? bsum[t] : 0;
    sh[t] = v; __syncthreads();
    #pragma unroll
    for (int off = 1; off < 256; off <<= 1) {
        int u = (t >= off) ? sh[t - off] : 0;
        __syncthreads();
        sh[t] += u; __syncthreads();
    }
    if (blockIdx.x == 0 && t == 0) { offs[n] = sh[nb - 1]; cursor[n] = sh[nb - 1]; }
    int base = (blockIdx.x > 0) ? sh[blockIdx.x - 1] : 0;
    __syncthreads();
    int i = blockIdx.x * 256 + t;
    if (i < n) {
        int o = offs[i] + base;
        offs[i] = o; cursor[i] = o;
    }
}

__global__ void k_fill(const int* __restrict__ ei, int E_in, int Etot, const int* flags,
                       int* cursor, int* s_src) {
    int e = blockIdx.x * blockDim.x + threadIdx.x;
    if (e >= Etot) return;
    int src, dst; edge_sd(ei, e, E_in, flags[1], src, dst);
    int p = atomicAdd(&cursor[dst], 1);
    s_src[p] = src;
}

// ---- fused dual MFMA GEMM with LDS-staged B, 8 waves/block, g-split across gridDim.y ----
// gridDim.y splits the output-column groups (GPB per block) to double block count:
// gemm<512> at 391 blocks was 1.5 blocks/CU -> 25% load-imbalance tail; 782 ~ 3/CU.
// Xraw: when non-null and flags[0]=1 the input is already bf16 -> read it directly
// (skips the 100MB x->xb round-trip in prep).
#define BPAD 136
template <int NOUT, int GPB>
__global__ __launch_bounds__(512) void k_gemm2(const ushort_t* __restrict__ X0,
                                               const ushort_t* __restrict__ Xraw,
                                               const int* __restrict__ flags,
                                               const ushort_t* __restrict__ WTl,
                                               const ushort_t* __restrict__ WTr,
                                               ushort_t* __restrict__ Yl,
                                               ushort_t* __restrict__ Yr, int M) {
    __shared__ ushort_t smem[2 * 64 * BPAD];
    const ushort_t* X = (Xraw && flags[0]) ? Xraw : X0;
    const int lane = threadIdx.x & 63, wid = threadIdx.x >> 6;
    const int rt = blockIdx.x * 8 + wid;
    const bool active = rt < (M >> 4);
    const int quad = lane >> 4, lo = lane & 15;
    const int g0 = blockIdx.y * GPB;

    bf16x8 afr[4];
    if (active) {
        const ushort_t* xrow = X + (size_t)(rt * 16 + lo) * 128 + quad * 8;
        #pragma unroll
        for (int kc = 0; kc < 4; kc++) afr[kc] = *(const bf16x8*)(xrow + kc * 32);
    }

    for (int gi = 0; gi < GPB; gi++) {
        int g = g0 + gi;
        __syncthreads();
        // cooperative stage: 2048 vectors (2 sides x 64 rows x 16 vecs), 4 per thread
        #pragma unroll
        for (int i = 0; i < 4; i++) {
            int vecid = threadIdx.x * 4 + i;
            int side = vecid >> 10, row = (vecid >> 4) & 63, v = vecid & 15;
            const ushort_t* src = (side ? WTr : WTl) + (size_t)(g * 64 + row) * 128 + v * 8;
            *(bf16x8*)(smem + (size_t)(side * 64 + row) * BPAD + v * 8) = *(const bf16x8*)src;
        }
        __syncthreads();
        if (!active) continue;
        #pragma unroll
        for (int side = 0; side < 2; side++) {
            ushort_t* Y = side ? Yr : Yl;
            f32x4 acc[4];
            #pragma unroll
            for (int nt = 0; nt < 4; nt++) acc[nt] = (f32x4){0.f, 0.f, 0.f, 0.f};
            #pragma unroll
            for (int nt = 0; nt < 4; nt++) {
                const ushort_t* brow = smem + (size_t)(side * 64 + nt * 16 + lo) * BPAD + quad * 8;
                #pragma unroll
                for (int kc = 0; kc < 4; kc++) {
                    bf16x8 b = *(const bf16x8*)(brow + kc * 32);
                    acc[nt] = __builtin_amdgcn_mfma_f32_16x16x32_bf16(afr[kc], b, acc[nt], 0, 0, 0);
                }
            }
            #pragma unroll
            for (int nt = 0; nt < 4; nt++) {
                int col = g * 64 + nt * 16 + lo;
                #pragma unroll
                for (int ri = 0; ri < 4; ri++) {
                    int row = rt * 16 + quad * 4 + ri;
                    Y[(size_t)row * NOUT + col] = f2bf(acc[nt][ri]);
                }
            }
        }
    }
}

// ======== layer 1 FUSED: slot-parallel exp-sum gather -> h1 (bf16), 3-deep pipeline ========
// wave per node. 4 slots x 16 lanes; lane covers 8 ch; head = (lane&15)>>2.
__global__ __launch_bounds__(256) void k_l1(const ushort_t* __restrict__ xl,
                                            const ushort_t* __restrict__ xr,
                                            const int* __restrict__ offs,
                                            const int* __restrict__ s_src,
                                            const float* __restrict__ att,
                                            const float* __restrict__ b1,
                                            int n, ushort_t* __restrict__ h1) {
    int lane = threadIdx.x & 63, wid = threadIdx.x >> 6;
    int node = blockIdx.x * 4 + wid;
    if (node >= n) return;
    int slot = lane >> 4, sub = lane & 15;
    int chb = sub * 8;
    uint_t cb = (uint_t)(sub * 16);     // byte offset of this lane's 8 channels

    uint4 xw = *(const uint4*)(xr + (size_t)node * 128 + chb);
    f32x2 xv[4] = {up2v(xw.x), up2v(xw.y), up2v(xw.z), up2v(xw.w)};
    f32x2 aL[4];
    #pragma unroll
    for (int j = 0; j < 4; j++) {
        f32x2 a = {att[chb + 2 * j], att[chb + 2 * j + 1]};
        aL[j] = a * (float)LOG2E;
    }

    int o0 = offs[node], o1 = offs[node + 1];
    float s = 0.f;
    f32x2 acc[4] = {{0.f,0.f},{0.f,0.f},{0.f,0.f},{0.f,0.f}};

    int i = o0 + slot;
    uint_t q0 = 0, q1 = 0;
    uint4 w0 = {0,0,0,0}, w1 = {0,0,0,0}, w2 = {0,0,0,0};
    if (i < o1)      w0 = ldu4(xl, (((uint_t)s_src[i])      << 8) + cb);
    if (i + 4 < o1)  w1 = ldu4(xl, (((uint_t)s_src[i + 4])  << 8) + cb);
    if (i + 8 < o1)  w2 = ldu4(xl, (((uint_t)s_src[i + 8])  << 8) + cb);
    if (i + 12 < o1) q0 = (((uint_t)s_src[i + 12]) << 8) + cb;
    if (i + 16 < o1) q1 = (((uint_t)s_src[i + 16]) << 8) + cb;

    while (i < o1) {
        uint4 wc = w0;
        w0 = w1; w1 = w2;
        if (i + 12 < o1) w2 = ldu4(xl, q0);
        q0 = q1;
        if (i + 20 < o1) q1 = (((uint_t)s_src[i + 20]) << 8) + cb;
        f32x2 v[4] = {up2v(wc.x), up2v(wc.y), up2v(wc.z), up2v(wc.w)};
        f32x2 es = {0.f, 0.f};
        #pragma unroll
        for (int j = 0; j < 4; j++) {
            f32x2 m = v[j] + xv[j];
            f32x2 l = __builtin_elementwise_max(m, m * NEG_SLOPE);
            es = __builtin_elementwise_fma(aL[j], l, es);
        }
        float e = es.x + es.y;
        e = dpp_add<0xB1>(e);               // xor 1
        e = dpp_add<0x4E>(e);               // xor 2 -> 4-lane head group reduced
        float p = __builtin_amdgcn_exp2f(fminf(e, 115.f));
        s += p;
        f32x2 pp = {p, p};
        #pragma unroll
        for (int j = 0; j < 4; j++)
            acc[j] = __builtin_elementwise_fma(pp, v[j], acc[j]);
        i += 4;
    }
    // merge the 4 slots: plain butterfly adds (once per node)
    #pragma unroll
    for (int off = 16; off <= 32; off <<= 1) {
        s += __shfl_xor(s, off, 64);
        #pragma unroll
        for (int j = 0; j < 4; j++) {
            f32x2 o = {__shfl_xor(acc[j].x, off, 64), __shfl_xor(acc[j].y, off, 64)};
            acc[j] += o;
        }
    }
    if (slot == 0) {
        float inv = 1.f / s;
        uint_t pk[4];
        #pragma unroll
        for (int j = 0; j < 4; j++) {
            float r0 = fmaxf(fmaf(acc[j].x, inv, b1[chb + 2 * j]),     0.f);
            float r1 = fmaxf(fmaf(acc[j].y, inv, b1[chb + 2 * j + 1]), 0.f);
            pk[j] = (uint_t)f2bf(r0) | ((uint_t)f2bf(r1) << 16);
        }
        *(uint4*)(h1 + (size_t)node * 128 + chb) = make_uint4(pk[0], pk[1], pk[2], pk[3]);
    }
}

// ======== layer 2 FUSED: one wave = one node, per-node blocks, 6-deep (R7 measured-best) ====
// CONVERGED at ~125us: R3/R5/R6/R7 (3 structures x 3 depths) all land 125-135us with
// VALU 60%, BW 46%, Occ 47% — random-1KB-gather fabric ceiling (~7 TB/s logical through
// L2, 424MB L2-miss). Do not re-tune without a traffic-reduction idea.
__global__ __launch_bounds__(256) void k_l2(const ushort_t* __restrict__ xl,
                                            const ushort_t* __restrict__ xr,
                                            const int* __restrict__ offs,
                                            const int* __restrict__ s_src,
                                            const float* __restrict__ att,
                                            const float* __restrict__ b2,
                                            const float* __restrict__ Wo,
                                            const float* __restrict__ bo,
                                            int n, const int* flags, void* dout) {
    int lane = threadIdx.x & 63, wid = threadIdx.x >> 6;
    int node = blockIdx.x * 4 + wid;
    if (node >= n) return;
    int h = lane >> 4, sub = lane & 15;
    int chb = sub * 8;                  // channel base within head
    int choff = h * 128 + chb;          // element offset within 512-elem row
    uint_t cb = (uint_t)(choff * 2);    // byte offset within 1KB row
    int bf = flags[0];

    uint4 xw = *(const uint4*)(xr + (size_t)node * 512 + choff);
    f32x2 xv[4] = {up2v(xw.x), up2v(xw.y), up2v(xw.z), up2v(xw.w)};
    f32x2 aL[4];
    #pragma unroll
    for (int j = 0; j < 4; j++) {
        f32x2 a = {att[choff + 2 * j], att[choff + 2 * j + 1]};
        aL[j] = a * (float)LOG2E;
    }

    int o0 = __builtin_amdgcn_readfirstlane(offs[node]);
    int o1 = __builtin_amdgcn_readfirstlane(offs[node + 1]);
    int cnt = o1 - o0;

    float s = 0.f;
    f32x2 acc[4] = {{0.f,0.f},{0.f,0.f},{0.f,0.f},{0.f,0.f}};
    const char* xlb = (const char*)xl;

    for (int base = 0; base < cnt; base += 64) {
        int m = cnt - base; if (m > 64) m = 64;
        int vidx = s_src[o0 + base + lane];     // 64 indices in one coalesced load

        auto ROW = [&](int k) -> uint4 {
            int kk = (k < m - 1) ? k : (m - 1);             // SALU clamp: re-load = L1 hit
            int idx = __builtin_amdgcn_readlane(vidx, kk);  // SGPR
            return *(const uint4*)(xlb + (((size_t)(uint_t)idx) << 10) + cb);
        };
        auto PROC = [&](const uint4& w) {
            f32x2 v[4] = {up2f(w.x), up2f(w.y), up2f(w.z), up2f(w.w)};
            f32x2 es = {0.f, 0.f};
            #pragma unroll
            for (int j = 0; j < 4; j++) {
                f32x2 mm = v[j] + xv[j];
                f32x2 l = __builtin_elementwise_max(mm, mm * NEG_SLOPE);
                es = __builtin_elementwise_fma(aL[j], l, es);
            }
            float e = es.x + es.y;
            e = dpp_add<0xB1>(e);   // xor 1
            e = dpp_add<0x4E>(e);   // xor 2
            e = dpp_add<0x141>(e);  // xor 4 (row_half_mirror; quads uniform)
            e = dpp_add<0x140>(e);  // xor 8 (row_mirror; 8-groups uniform)
            float p = __builtin_amdgcn_exp2f(fminf(e, 115.f));
            s += p;
            f32x2 pp = {p, p};
            #pragma unroll
            for (int j = 0; j < 4; j++)
                acc[j] = __builtin_elementwise_fma(pp, v[j], acc[j]);
        };

        uint4 wA = ROW(0), wB = ROW(1), wC = ROW(2);
        uint4 wD = ROW(3), wE = ROW(4), wF = ROW(5);
        int k = 0;
        for (; k + 6 <= m; k += 6) {
            uint4 tA = ROW(k + 6);  PROC(wA); wA = tA;
            uint4 tB = ROW(k + 7);  PROC(wB); wB = tB;
            uint4 tC = ROW(k + 8);  PROC(wC); wC = tC;
            uint4 tD = ROW(k + 9);  PROC(wD); wD = tD;
            uint4 tE = ROW(k + 10); PROC(wE); wE = tE;
            uint4 tF = ROW(k + 11); PROC(wF); wF = tF;
        }
        if (k < m)     PROC(wA);
        if (k + 1 < m) PROC(wB);
        if (k + 2 < m) PROC(wC);
        if (k + 3 < m) PROC(wD);
        if (k + 4 < m) PROC(wE);
    }

    // normalize per head (s uniform within each 16-lane group), then mean over heads
    float inv = 1.f / s;
    f32x2 iv = {inv, inv};
    #pragma unroll
    for (int j = 0; j < 4; j++) acc[j] = acc[j] * iv;
    #pragma unroll
    for (int off = 16; off <= 32; off <<= 1) {
        #pragma unroll
        for (int j = 0; j < 4; j++) {
            f32x2 o = {__shfl_xor(acc[j].x, off, 64), __shfl_xor(acc[j].y, off, 64)};
            acc[j] += o;
        }
    }
    float hm[8];
    #pragma unroll
    for (int j = 0; j < 4; j++) {
        hm[2 * j]     = 0.25f * acc[j].x + b2[chb + 2 * j];
        hm[2 * j + 1] = 0.25f * acc[j].y + b2[chb + 2 * j + 1];
    }

    if (h == 0) {   // 16 lanes write the 128-ch embedding row
        size_t ob = (size_t)n * 2 + (size_t)node * 128 + chb;
        if (bf) {
            uint_t pk[4];
            #pragma unroll
            for (int j = 0; j < 4; j++)
                pk[j] = (uint_t)f2bf(hm[2 * j]) | ((uint_t)f2bf(hm[2 * j + 1]) << 16);
            *(uint4*)((ushort_t*)dout + ob) = make_uint4(pk[0], pk[1], pk[2], pk[3]);
        } else {
            float* fp = (float*)dout + ob;
            *(float4*)fp       = make_float4(hm[0], hm[1], hm[2], hm[3]);
            *(float4*)(fp + 4) = make_float4(hm[4], hm[5], hm[6], hm[7]);
        }
    }

    // decoder: all lanes compute (every 16-group holds the full mean), lane 0 writes
    float d0 = 0.f, d1 = 0.f;
    #pragma unroll
    for (int c = 0; c < 8; c++) {
        float w0 = Wo[(chb + c) * 2], w1 = Wo[(chb + c) * 2 + 1];
        d0 = fmaf(hm[c], w0, d0);
        d1 = fmaf(hm[c], w1, d1);
    }
    d0 = dpp_add<0xB1>(d0); d0 = dpp_add<0x4E>(d0); d0 = dpp_add<0x141>(d0); d0 = dpp_add<0x140>(d0);
    d1 = dpp_add<0xB1>(d1); d1 = dpp_add<0x4E>(d1); d1 = dpp_add<0x141>(d1); d1 = dpp_add<0x140>(d1);
    if (lane == 0) {
        float r0 = d0 + bo[0], r1 = d1 + bo[1];
        size_t oidx = (size_t)node * 2;
        if (bf) { ((ushort_t*)dout)[oidx] = f2bf(r0); ((ushort_t*)dout)[oidx + 1] = f2bf(r1); }
        else    { ((float*)dout)[oidx]    = r0;       ((float*)dout)[oidx + 1]    = r1; }
    }
}

extern "C" void kernel_launch(void* const* d_in, const int* in_sizes, int n_in,
                              void* d_out, int out_size, void* d_ws, size_t ws_size,
                              hipStream_t stream) {
    const void* x    = d_in[0];
    const int*  ei   = (const int*)d_in[1];
    const void* Wl1  = d_in[2];
    const void* Wr1  = d_in[3];
    const void* att1 = d_in[4];
    const void* b1   = d_in[5];
    const void* Wl2  = d_in[6];
    const void* Wr2  = d_in[7];
    const void* att2 = d_in[8];
    const void* b2   = d_in[9];
    const void* Wo   = d_in[10];
    const void* bo   = d_in[11];

    const int N    = in_sizes[0] / 128;   // 50000
    const int E_in = in_sizes[1] / 2;     // 800000
    const int Etot = E_in + N;

    const int sW1 = in_sizes[2], sW2 = in_sizes[6];
    const int satt1 = in_sizes[4], sb1 = in_sizes[5];
    const int satt2 = in_sizes[8], sb2 = in_sizes[9];
    const int sWo = in_sizes[10], sbo = in_sizes[11];

    char* w = (char*)d_ws;
    size_t off = 0;
    auto take = [&](size_t bytes) -> void* {
        void* p = w + off;
        off += (bytes + 255) & ~(size_t)255;
        return p;
    };
    int*      flags  = (int*)take(256);
    ushort_t* xb     = (ushort_t*)take((size_t)N * 128 * sizeof(ushort_t));
    ushort_t* WTl1   = (ushort_t*)take((size_t)sW1 * 2);
    ushort_t* WTr1   = (ushort_t*)take((size_t)sW1 * 2);
    ushort_t* WTl2   = (ushort_t*)take((size_t)sW2 * 2);
    ushort_t* WTr2   = (ushort_t*)take((size_t)sW2 * 2);
    float*    att1f  = (float*)take((size_t)satt1 * 4);
    float*    b1f    = (float*)take((size_t)sb1 * 4);
    float*    att2f  = (float*)take((size_t)satt2 * 4);
    float*    b2f    = (float*)take((size_t)sb2 * 4);
    float*    Wof    = (float*)take((size_t)sWo * 4);
    float*    bof    = (float*)take((size_t)sbo * 4);
    int*      deg    = (int*)take((size_t)N * sizeof(int));
    int*      offs   = (int*)take((size_t)(N + 1) * sizeof(int));
    int*      cursor = (int*)take((size_t)(N + 1) * sizeof(int));
    int*      bsum   = (int*)take(1024);
    int*      s_src  = (int*)take((size_t)(Etot + 64) * sizeof(int));  // +64 pad
    ushort_t* h1     = (ushort_t*)take((size_t)N * 128 * sizeof(ushort_t));
    ushort_t* xl1b   = (ushort_t*)take((size_t)N * 128 * sizeof(ushort_t));
    ushort_t* xr1b   = (ushort_t*)take((size_t)N * 128 * sizeof(ushort_t));
    ushort_t* xl2b   = (ushort_t*)take((size_t)N * 512 * sizeof(ushort_t));
    ushort_t* xr2b   = (ushort_t*)take((size_t)N * 512 * sizeof(ushort_t));

    dim3 b256(256), b512(512);
    const int nb = (N + 255) / 256;       // 196 scan blocks

    k_detect<<<1, b256, 0, stream>>>((const uint_t*)x, ei, flags);
    hipMemsetAsync(deg, 0, (size_t)N * sizeof(int), stream);
    hipMemsetAsync(s_src + Etot, 0, 64 * sizeof(int), stream);   // pad -> valid row 0

    long prep_total = (long)Etot + (long)N * 16 + 2L * sW1 + 2L * sW2
                    + satt1 + sb1 + satt2 + sb2 + sWo + sbo;
    int prep_blocks = (int)((prep_total + 255) / 256);
    k_prep<<<prep_blocks, b256, 0, stream>>>(x, Wl1, Wr1, att1, b1, Wl2, Wr2, att2, b2, Wo, bo,
                                             ei, E_in, Etot, deg, xb, WTl1, WTr1, WTl2, WTr2,
                                             att1f, b1f, att2f, b2f, Wof, bof,
                                             N, sW1, sW2, satt1, sb1, satt2, sb2, sWo, sbo, flags);

    k_scanA<<<nb, b256, 0, stream>>>(deg, offs, bsum, N);
    k_scanBC<<<nb, b256, 0, stream>>>(offs, cursor, bsum, nb, N);
    k_fill<<<(Etot + 255) / 256, b256, 0, stream>>>(ei, E_in, Etot, flags, cursor, s_src);

    dim3 gg128((N / 16 + 7) / 8, 2);      // 782 blocks: g-split 2 x 1 group
    k_gemm2<128, 1><<<gg128, b512, 0, stream>>>(xb, (const ushort_t*)x, flags,
                                                WTl1, WTr1, xl1b, xr1b, N);
    k_l1<<<(N + 3) / 4, b256, 0, stream>>>(xl1b, xr1b, offs, s_src, att1f, b1f, N, h1);

    dim3 gg512((N / 16 + 7) / 8, 2);      // 782 blocks: g-split 2 x 4 groups
    k_gemm2<512, 4><<<gg512, b512, 0, stream>>>(h1, nullptr, flags,
                                                WTl2, WTr2, xl2b, xr2b, N);

    k_l2<<<(N + 3) / 4, b256, 0, stream>>>(xl2b, xr2b, offs, s_src, att2f, b2f, Wof, bof, N, flags, d_out);
}

// Round 10
// 394.378 us; speedup vs baseline: 1.0129x; 1.0129x over previous
//
#include <hip/hip_runtime.h>

#define NEG_SLOPE 0.2f
#define LOG2E 1.44269504088896340736f

typedef unsigned short ushort_t;
typedef unsigned int uint_t;
typedef __attribute__((ext_vector_type(8))) short bf16x8;   // 8 bf16 in 4 VGPRs
typedef __attribute__((ext_vector_type(4))) float f32x4;
typedef __attribute__((ext_vector_type(2))) float f32x2;    // maps to v_pk_*_f32 on gfx950

__device__ inline float bf2f(ushort_t u) { union { uint_t i; float f; } v; v.i = ((uint_t)u) << 16; return v.f; }
__device__ inline ushort_t f2bf(float f) {
    union { float f; uint_t u; } v; v.f = f;
    uint_t r = v.u + 0x7fffu + ((v.u >> 16) & 1u);
    return (ushort_t)(r >> 16);
}
// unpack 2 packed bf16 -> f32x2 (exact: shl + and)
__device__ inline f32x2 up2v(uint_t w) {
    union { uint_t i; float f; } lo, hi;
    lo.i = w << 16; hi.i = w & 0xFFFF0000u;
    return (f32x2){lo.f, hi.f};
}
// fast unpack: hi word used unmasked (adds <=0.5 ulp-of-bf16 mantissa noise; saves the AND)
__device__ inline f32x2 up2f(uint_t w) {
    union { uint_t i; float f; } lo, hi;
    lo.i = w << 16; hi.i = w;
    return (f32x2){lo.f, hi.f};
}
// dtype-flexible loads (bf=1: buffer holds bf16; bf=0: fp32)
__device__ inline float ld_f(const void* p, size_t i, int bf) { return bf ? bf2f(((const ushort_t*)p)[i]) : ((const float*)p)[i]; }
__device__ inline ushort_t ld_b(const void* p, size_t i, int bf) { return bf ? ((const ushort_t*)p)[i] : f2bf(((const float*)p)[i]); }
// edge fetch with int64/int32 handling; self-loops appended at e >= E_in
__device__ inline void edge_sd(const int* __restrict__ ei, int e, int E_in, int i64, int& src, int& dst) {
    if (e < E_in) {
        if (i64) { src = ei[2 * (size_t)e]; dst = ei[2 * ((size_t)E_in + e)]; }
        else     { src = ei[e];             dst = ei[(size_t)E_in + e]; }
    } else { src = dst = e - E_in; }
}

// butterfly add via DPP (pure VALU, no DS pipe). 0xB1=xor1, 0x4E=xor2,
// 0x141=row_half_mirror (==xor4 once quads uniform), 0x140=row_mirror (==xor8 once
// 8-groups uniform). All stay within a 16-lane DPP row.
template <int CTRL>
__device__ inline float dpp_add(float v) {
    union { float f; int i; } u, r;
    u.f = v;
    r.i = __builtin_amdgcn_update_dpp(0, u.i, CTRL, 0xF, 0xF, true);
    return v + r.f;
}

// 16B gather with uniform base + 32-bit byte offset (SADDR form, no 64-bit VALU adds)
__device__ inline uint4 ldu4(const ushort_t* __restrict__ base, uint_t boff) {
    return *(const uint4*)((const char*)base + (size_t)boff);
}

// ---------------- dtype detection ----------------
__global__ void k_detect(const uint_t* __restrict__ xw, const int* __restrict__ ei, int* flags) {
    __shared__ int cnt;
    if (threadIdx.x == 0) cnt = 0;
    __syncthreads();
    uint_t w = xw[threadIdx.x];
    int eb = (int)((w >> 7) & 0xFFu);
    if (eb >= 113 && eb <= 142) atomicAdd(&cnt, 1);
    __syncthreads();
    if (threadIdx.x == 0) {
        flags[0] = (cnt > 128) ? 1 : 0;
        int z = 0;
        #pragma unroll
        for (int i = 1; i < 16; i += 2) z += (ei[i] == 0) ? 1 : 0;
        flags[1] = (z == 8) ? 1 : 0;
    }
}

// ------ fused front-end: degree count | cvt x->bf16 (x8 vectorized) | build WT | params ------
__global__ __launch_bounds__(256) void k_prep(const void* __restrict__ x, const void* Wl1, const void* Wr1,
                      const void* att1, const void* b1, const void* Wl2, const void* Wr2,
                      const void* att2, const void* b2, const void* Wo, const void* bo,
                      const int* __restrict__ ei, int E_in, int Etot, int* deg, ushort_t* xb,
                      ushort_t* WTl1, ushort_t* WTr1, ushort_t* WTl2, ushort_t* WTr2,
                      float* att1f, float* b1f, float* att2f, float* b2f, float* Wof, float* bof,
                      int N, int sW1, int sW2, int satt1, int sb1, int satt2, int sb2, int sWo, int sbo,
                      const int* flags) {
    int bf = flags[0];
    long r = (long)blockIdx.x * 256 + threadIdx.x;
    if (r < Etot) {   // degree count
        int e = (int)r, dst;
        if (e < E_in) dst = flags[1] ? ei[2 * ((size_t)E_in + e)] : ei[(size_t)E_in + e];
        else          dst = e - E_in;
        atomicAdd(&deg[dst], 1);
        return;
    }
    r -= Etot;
    long nx8 = (long)N * 16;    // 8-element chunks of x
    if (r < nx8) {
        size_t base = (size_t)r * 8;
        if (bf) {
            *(uint4*)(xb + base) = *(const uint4*)((const ushort_t*)x + base);
        } else {
            const float* xf = (const float*)x + base;
            float4 a = *(const float4*)xf;
            float4 c = *(const float4*)(xf + 4);
            uint_t pk[4];
            pk[0] = (uint_t)f2bf(a.x) | ((uint_t)f2bf(a.y) << 16);
            pk[1] = (uint_t)f2bf(a.z) | ((uint_t)f2bf(a.w) << 16);
            pk[2] = (uint_t)f2bf(c.x) | ((uint_t)f2bf(c.y) << 16);
            pk[3] = (uint_t)f2bf(c.z) | ((uint_t)f2bf(c.w) << 16);
            *(uint4*)(xb + base) = make_uint4(pk[0], pk[1], pk[2], pk[3]);
        }
        return;
    }
    r -= nx8;
    if (r < sW1) { int n = r >> 7, k = r & 127; WTl1[r] = ld_b(Wl1, (size_t)k * 128 + n, bf); return; } r -= sW1;
    if (r < sW1) { int n = r >> 7, k = r & 127; WTr1[r] = ld_b(Wr1, (size_t)k * 128 + n, bf); return; } r -= sW1;
    if (r < sW2) { int n = r >> 7, k = r & 127; WTl2[r] = ld_b(Wl2, (size_t)k * 512 + n, bf); return; } r -= sW2;
    if (r < sW2) { int n = r >> 7, k = r & 127; WTr2[r] = ld_b(Wr2, (size_t)k * 512 + n, bf); return; } r -= sW2;
    if (r < satt1) { att1f[r] = ld_f(att1, r, bf); return; } r -= satt1;
    if (r < sb1)   { b1f[r]   = ld_f(b1, r, bf);   return; } r -= sb1;
    if (r < satt2) { att2f[r] = ld_f(att2, r, bf); return; } r -= satt2;
    if (r < sb2)   { b2f[r]   = ld_f(b2, r, bf);   return; } r -= sb2;
    if (r < sWo)   { Wof[r]   = ld_f(Wo, r, bf);   return; } r -= sWo;
    if (r < sbo)   { bof[r]   = ld_f(bo, r, bf);   return; }
}

// -------- hierarchical exclusive scan --------
__global__ __launch_bounds__(256) void k_scanA(const int* __restrict__ deg, int* offs, int* bsum, int n) {
    __shared__ int sh[256];
    int t = threadIdx.x;
    int i = blockIdx.x * 256 + t;
    int v = (i < n) ? deg[i] : 0;
    sh[t] = v; __syncthreads();
    #pragma unroll
    for (int off = 1; off < 256; off <<= 1) {
        int u = (t >= off) ? sh[t - off] : 0;
        __syncthreads();
        sh[t] += u; __syncthreads();
    }
    if (i < n) offs[i] = sh[t] - v;
    if (t == 255) bsum[blockIdx.x] = sh[255];
}

__global__ __launch_bounds__(256) void k_scanBC(int* offs, int* cursor, const int* __restrict__ bsum,
                                                int nb, int n) {
    __shared__ int sh[256];
    int t = threadIdx.x;
    int v = (t < nb) ? bsum[t] : 0;
    sh[t] = v; __syncthreads();
    #pragma unroll
    for (int off = 1; off < 256; off <<= 1) {
        int u = (t >= off) ? sh[t - off] : 0;
        __syncthreads();
        sh[t] += u; __syncthreads();
    }
    if (blockIdx.x == 0 && t == 0) { offs[n] = sh[nb - 1]; cursor[n] = sh[nb - 1]; }
    int base = (blockIdx.x > 0) ? sh[blockIdx.x - 1] : 0;
    __syncthreads();
    int i = blockIdx.x * 256 + t;
    if (i < n) {
        int o = offs[i] + base;
        offs[i] = o; cursor[i] = o;
    }
}

__global__ void k_fill(const int* __restrict__ ei, int E_in, int Etot, const int* flags,
                       int* cursor, int* s_src) {
    int e = blockIdx.x * blockDim.x + threadIdx.x;
    if (e >= Etot) return;
    int src, dst; edge_sd(ei, e, E_in, flags[1], src, dst);
    int p = atomicAdd(&cursor[dst], 1);
    s_src[p] = src;
}

// ---- fused dual MFMA GEMM with LDS-staged B, 8 waves/block ----
// 512 threads: the per-g B-stage (32KB, 2 barriers) is shared by 8 waves instead of 4,
// halving staging instructions + barrier count per output element.
#define BPAD 136
template <int NOUT>
__global__ __launch_bounds__(512) void k_gemm2(const ushort_t* __restrict__ X,
                                               const ushort_t* __restrict__ WTl,
                                               const ushort_t* __restrict__ WTr,
                                               ushort_t* __restrict__ Yl,
                                               ushort_t* __restrict__ Yr, int M) {
    __shared__ ushort_t smem[2 * 64 * BPAD];
    const int lane = threadIdx.x & 63, wid = threadIdx.x >> 6;
    const int rt = blockIdx.x * 8 + wid;
    const bool active = rt < (M >> 4);
    const int quad = lane >> 4, lo = lane & 15;

    bf16x8 afr[4];
    if (active) {
        const ushort_t* xrow = X + (size_t)(rt * 16 + lo) * 128 + quad * 8;
        #pragma unroll
        for (int kc = 0; kc < 4; kc++) afr[kc] = *(const bf16x8*)(xrow + kc * 32);
    }

    for (int g = 0; g < NOUT / 64; g++) {
        __syncthreads();
        // cooperative stage: 2048 vectors (2 sides x 64 rows x 16 vecs), 4 per thread
        #pragma unroll
        for (int i = 0; i < 4; i++) {
            int vecid = threadIdx.x * 4 + i;
            int side = vecid >> 10, row = (vecid >> 4) & 63, v = vecid & 15;
            const ushort_t* src = (side ? WTr : WTl) + (size_t)(g * 64 + row) * 128 + v * 8;
            *(bf16x8*)(smem + (size_t)(side * 64 + row) * BPAD + v * 8) = *(const bf16x8*)src;
        }
        __syncthreads();
        if (!active) continue;
        #pragma unroll
        for (int side = 0; side < 2; side++) {
            ushort_t* Y = side ? Yr : Yl;
            f32x4 acc[4];
            #pragma unroll
            for (int nt = 0; nt < 4; nt++) acc[nt] = (f32x4){0.f, 0.f, 0.f, 0.f};
            #pragma unroll
            for (int nt = 0; nt < 4; nt++) {
                const ushort_t* brow = smem + (size_t)(side * 64 + nt * 16 + lo) * BPAD + quad * 8;
                #pragma unroll
                for (int kc = 0; kc < 4; kc++) {
                    bf16x8 b = *(const bf16x8*)(brow + kc * 32);
                    acc[nt] = __builtin_amdgcn_mfma_f32_16x16x32_bf16(afr[kc], b, acc[nt], 0, 0, 0);
                }
            }
            #pragma unroll
            for (int nt = 0; nt < 4; nt++) {
                int col = g * 64 + nt * 16 + lo;
                #pragma unroll
                for (int ri = 0; ri < 4; ri++) {
                    int row = rt * 16 + quad * 4 + ri;
                    Y[(size_t)row * NOUT + col] = f2bf(acc[nt][ri]);
                }
            }
        }
    }
}

// ======== layer 1 FUSED: slot-parallel exp-sum gather -> h1 (bf16), 3-deep pipeline ========
// wave per node. 4 slots x 16 lanes; lane covers 8 ch; head = (lane&15)>>2.
// Pipeline deepened 2->3 rows in flight per slot (12 edges in flight/wave) — k_l2's
// MLP lesson; +4 VGPR, stays well under the 64-reg occupancy cliff.
__global__ __launch_bounds__(256) void k_l1(const ushort_t* __restrict__ xl,
                                            const ushort_t* __restrict__ xr,
                                            const int* __restrict__ offs,
                                            const int* __restrict__ s_src,
                                            const float* __restrict__ att,
                                            const float* __restrict__ b1,
                                            int n, ushort_t* __restrict__ h1) {
    int lane = threadIdx.x & 63, wid = threadIdx.x >> 6;
    int node = blockIdx.x * 4 + wid;
    if (node >= n) return;
    int slot = lane >> 4, sub = lane & 15;
    int chb = sub * 8;
    uint_t cb = (uint_t)(sub * 16);     // byte offset of this lane's 8 channels

    uint4 xw = *(const uint4*)(xr + (size_t)node * 128 + chb);
    f32x2 xv[4] = {up2v(xw.x), up2v(xw.y), up2v(xw.z), up2v(xw.w)};
    f32x2 aL[4];
    #pragma unroll
    for (int j = 0; j < 4; j++) {
        f32x2 a = {att[chb + 2 * j], att[chb + 2 * j + 1]};
        aL[j] = a * (float)LOG2E;
    }

    int o0 = offs[node], o1 = offs[node + 1];
    float s = 0.f;
    f32x2 acc[4] = {{0.f,0.f},{0.f,0.f},{0.f,0.f},{0.f,0.f}};

    int i = o0 + slot;
    uint_t q0 = 0, q1 = 0;
    uint4 w0 = {0,0,0,0}, w1 = {0,0,0,0}, w2 = {0,0,0,0};
    if (i < o1)      w0 = ldu4(xl, (((uint_t)s_src[i])      << 8) + cb);
    if (i + 4 < o1)  w1 = ldu4(xl, (((uint_t)s_src[i + 4])  << 8) + cb);
    if (i + 8 < o1)  w2 = ldu4(xl, (((uint_t)s_src[i + 8])  << 8) + cb);
    if (i + 12 < o1) q0 = (((uint_t)s_src[i + 12]) << 8) + cb;
    if (i + 16 < o1) q1 = (((uint_t)s_src[i + 16]) << 8) + cb;

    while (i < o1) {
        uint4 wc = w0;
        w0 = w1; w1 = w2;
        if (i + 12 < o1) w2 = ldu4(xl, q0);
        q0 = q1;
        if (i + 20 < o1) q1 = (((uint_t)s_src[i + 20]) << 8) + cb;
        f32x2 v[4] = {up2v(wc.x), up2v(wc.y), up2v(wc.z), up2v(wc.w)};
        f32x2 es = {0.f, 0.f};
        #pragma unroll
        for (int j = 0; j < 4; j++) {
            f32x2 m = v[j] + xv[j];
            f32x2 l = __builtin_elementwise_max(m, m * NEG_SLOPE);
            es = __builtin_elementwise_fma(aL[j], l, es);
        }
        float e = es.x + es.y;
        e = dpp_add<0xB1>(e);               // xor 1
        e = dpp_add<0x4E>(e);               // xor 2 -> 4-lane head group reduced
        float p = __builtin_amdgcn_exp2f(fminf(e, 115.f));
        s += p;
        f32x2 pp = {p, p};
        #pragma unroll
        for (int j = 0; j < 4; j++)
            acc[j] = __builtin_elementwise_fma(pp, v[j], acc[j]);
        i += 4;
    }
    // merge the 4 slots: plain butterfly adds (once per node)
    #pragma unroll
    for (int off = 16; off <= 32; off <<= 1) {
        s += __shfl_xor(s, off, 64);
        #pragma unroll
        for (int j = 0; j < 4; j++) {
            f32x2 o = {__shfl_xor(acc[j].x, off, 64), __shfl_xor(acc[j].y, off, 64)};
            acc[j] += o;
        }
    }
    if (slot == 0) {
        float inv = 1.f / s;
        uint_t pk[4];
        #pragma unroll
        for (int j = 0; j < 4; j++) {
            float r0 = fmaxf(fmaf(acc[j].x, inv, b1[chb + 2 * j]),     0.f);
            float r1 = fmaxf(fmaf(acc[j].y, inv, b1[chb + 2 * j + 1]), 0.f);
            pk[j] = (uint_t)f2bf(r0) | ((uint_t)f2bf(r1) << 16);
        }
        *(uint4*)(h1 + (size_t)node * 128 + chb) = make_uint4(pk[0], pk[1], pk[2], pk[3]);
    }
}

// ======== layer 2 FUSED: one wave = one node, per-node blocks, 6-deep (R7 measured-best) ====
// CONVERGED at ~125us: R3/R5/R6/R7 (3 structures x 3 depths) all land 125-135us with
// VALU 60%, BW 46%, Occ 47% — random-1KB-gather fabric ceiling (~7 TB/s logical through
// L2, 424MB L2-miss). Do not re-tune without a traffic-reduction idea.
__global__ __launch_bounds__(256) void k_l2(const ushort_t* __restrict__ xl,
                                            const ushort_t* __restrict__ xr,
                                            const int* __restrict__ offs,
                                            const int* __restrict__ s_src,
                                            const float* __restrict__ att,
                                            const float* __restrict__ b2,
                                            const float* __restrict__ Wo,
                                            const float* __restrict__ bo,
                                            int n, const int* flags, void* dout) {
    int lane = threadIdx.x & 63, wid = threadIdx.x >> 6;
    int node = blockIdx.x * 4 + wid;
    if (node >= n) return;
    int h = lane >> 4, sub = lane & 15;
    int chb = sub * 8;                  // channel base within head
    int choff = h * 128 + chb;          // element offset within 512-elem row
    uint_t cb = (uint_t)(choff * 2);    // byte offset within 1KB row
    int bf = flags[0];

    uint4 xw = *(const uint4*)(xr + (size_t)node * 512 + choff);
    f32x2 xv[4] = {up2v(xw.x), up2v(xw.y), up2v(xw.z), up2v(xw.w)};
    f32x2 aL[4];
    #pragma unroll
    for (int j = 0; j < 4; j++) {
        f32x2 a = {att[choff + 2 * j], att[choff + 2 * j + 1]};
        aL[j] = a * (float)LOG2E;
    }

    int o0 = __builtin_amdgcn_readfirstlane(offs[node]);
    int o1 = __builtin_amdgcn_readfirstlane(offs[node + 1]);
    int cnt = o1 - o0;

    float s = 0.f;
    f32x2 acc[4] = {{0.f,0.f},{0.f,0.f},{0.f,0.f},{0.f,0.f}};
    const char* xlb = (const char*)xl;

    for (int base = 0; base < cnt; base += 64) {
        int m = cnt - base; if (m > 64) m = 64;
        int vidx = s_src[o0 + base + lane];     // 64 indices in one coalesced load

        auto ROW = [&](int k) -> uint4 {
            int kk = (k < m - 1) ? k : (m - 1);             // SALU clamp: re-load = L1 hit
            int idx = __builtin_amdgcn_readlane(vidx, kk);  // SGPR
            return *(const uint4*)(xlb + (((size_t)(uint_t)idx) << 10) + cb);
        };
        auto PROC = [&](const uint4& w) {
            f32x2 v[4] = {up2f(w.x), up2f(w.y), up2f(w.z), up2f(w.w)};
            f32x2 es = {0.f, 0.f};
            #pragma unroll
            for (int j = 0; j < 4; j++) {
                f32x2 mm = v[j] + xv[j];
                f32x2 l = __builtin_elementwise_max(mm, mm * NEG_SLOPE);
                es = __builtin_elementwise_fma(aL[j], l, es);
            }
            float e = es.x + es.y;
            e = dpp_add<0xB1>(e);   // xor 1
            e = dpp_add<0x4E>(e);   // xor 2
            e = dpp_add<0x141>(e);  // xor 4 (row_half_mirror; quads uniform)
            e = dpp_add<0x140>(e);  // xor 8 (row_mirror; 8-groups uniform)
            float p = __builtin_amdgcn_exp2f(fminf(e, 115.f));
            s += p;
            f32x2 pp = {p, p};
            #pragma unroll
            for (int j = 0; j < 4; j++)
                acc[j] = __builtin_elementwise_fma(pp, v[j], acc[j]);
        };

        uint4 wA = ROW(0), wB = ROW(1), wC = ROW(2);
        uint4 wD = ROW(3), wE = ROW(4), wF = ROW(5);
        int k = 0;
        for (; k + 6 <= m; k += 6) {
            uint4 tA = ROW(k + 6);  PROC(wA); wA = tA;
            uint4 tB = ROW(k + 7);  PROC(wB); wB = tB;
            uint4 tC = ROW(k + 8);  PROC(wC); wC = tC;
            uint4 tD = ROW(k + 9);  PROC(wD); wD = tD;
            uint4 tE = ROW(k + 10); PROC(wE); wE = tE;
            uint4 tF = ROW(k + 11); PROC(wF); wF = tF;
        }
        if (k < m)     PROC(wA);
        if (k + 1 < m) PROC(wB);
        if (k + 2 < m) PROC(wC);
        if (k + 3 < m) PROC(wD);
        if (k + 4 < m) PROC(wE);
    }

    // normalize per head (s uniform within each 16-lane group), then mean over heads
    float inv = 1.f / s;
    f32x2 iv = {inv, inv};
    #pragma unroll
    for (int j = 0; j < 4; j++) acc[j] = acc[j] * iv;
    #pragma unroll
    for (int off = 16; off <= 32; off <<= 1) {
        #pragma unroll
        for (int j = 0; j < 4; j++) {
            f32x2 o = {__shfl_xor(acc[j].x, off, 64), __shfl_xor(acc[j].y, off, 64)};
            acc[j] += o;
        }
    }
    float hm[8];
    #pragma unroll
    for (int j = 0; j < 4; j++) {
        hm[2 * j]     = 0.25f * acc[j].x + b2[chb + 2 * j];
        hm[2 * j + 1] = 0.25f * acc[j].y + b2[chb + 2 * j + 1];
    }

    if (h == 0) {   // 16 lanes write the 128-ch embedding row
        size_t ob = (size_t)n * 2 + (size_t)node * 128 + chb;
        if (bf) {
            uint_t pk[4];
            #pragma unroll
            for (int j = 0; j < 4; j++)
                pk[j] = (uint_t)f2bf(hm[2 * j]) | ((uint_t)f2bf(hm[2 * j + 1]) << 16);
            *(uint4*)((ushort_t*)dout + ob) = make_uint4(pk[0], pk[1], pk[2], pk[3]);
        } else {
            float* fp = (float*)dout + ob;
            *(float4*)fp       = make_float4(hm[0], hm[1], hm[2], hm[3]);
            *(float4*)(fp + 4) = make_float4(hm[4], hm[5], hm[6], hm[7]);
        }
    }

    // decoder: all lanes compute (every 16-group holds the full mean), lane 0 writes
    float d0 = 0.f, d1 = 0.f;
    #pragma unroll
    for (int c = 0; c < 8; c++) {
        float w0 = Wo[(chb + c) * 2], w1 = Wo[(chb + c) * 2 + 1];
        d0 = fmaf(hm[c], w0, d0);
        d1 = fmaf(hm[c], w1, d1);
    }
    d0 = dpp_add<0xB1>(d0); d0 = dpp_add<0x4E>(d0); d0 = dpp_add<0x141>(d0); d0 = dpp_add<0x140>(d0);
    d1 = dpp_add<0xB1>(d1); d1 = dpp_add<0x4E>(d1); d1 = dpp_add<0x141>(d1); d1 = dpp_add<0x140>(d1);
    if (lane == 0) {
        float r0 = d0 + bo[0], r1 = d1 + bo[1];
        size_t oidx = (size_t)node * 2;
        if (bf) { ((ushort_t*)dout)[oidx] = f2bf(r0); ((ushort_t*)dout)[oidx + 1] = f2bf(r1); }
        else    { ((float*)dout)[oidx]    = r0;       ((float*)dout)[oidx + 1]    = r1; }
    }
}

extern "C" void kernel_launch(void* const* d_in, const int* in_sizes, int n_in,
                              void* d_out, int out_size, void* d_ws, size_t ws_size,
                              hipStream_t stream) {
    const void* x    = d_in[0];
    const int*  ei   = (const int*)d_in[1];
    const void* Wl1  = d_in[2];
    const void* Wr1  = d_in[3];
    const void* att1 = d_in[4];
    const void* b1   = d_in[5];
    const void* Wl2  = d_in[6];
    const void* Wr2  = d_in[7];
    const void* att2 = d_in[8];
    const void* b2   = d_in[9];
    const void* Wo   = d_in[10];
    const void* bo   = d_in[11];

    const int N    = in_sizes[0] / 128;   // 50000
    const int E_in = in_sizes[1] / 2;     // 800000
    const int Etot = E_in + N;

    const int sW1 = in_sizes[2], sW2 = in_sizes[6];
    const int satt1 = in_sizes[4], sb1 = in_sizes[5];
    const int satt2 = in_sizes[8], sb2 = in_sizes[9];
    const int sWo = in_sizes[10], sbo = in_sizes[11];

    char* w = (char*)d_ws;
    size_t off = 0;
    auto take = [&](size_t bytes) -> void* {
        void* p = w + off;
        off += (bytes + 255) & ~(size_t)255;
        return p;
    };
    int*      flags  = (int*)take(256);
    ushort_t* xb     = (ushort_t*)take((size_t)N * 128 * sizeof(ushort_t));
    ushort_t* WTl1   = (ushort_t*)take((size_t)sW1 * 2);
    ushort_t* WTr1   = (ushort_t*)take((size_t)sW1 * 2);
    ushort_t* WTl2   = (ushort_t*)take((size_t)sW2 * 2);
    ushort_t* WTr2   = (ushort_t*)take((size_t)sW2 * 2);
    float*    att1f  = (float*)take((size_t)satt1 * 4);
    float*    b1f    = (float*)take((size_t)sb1 * 4);
    float*    att2f  = (float*)take((size_t)satt2 * 4);
    float*    b2f    = (float*)take((size_t)sb2 * 4);
    float*    Wof    = (float*)take((size_t)sWo * 4);
    float*    bof    = (float*)take((size_t)sbo * 4);
    int*      deg    = (int*)take((size_t)N * sizeof(int));
    int*      offs   = (int*)take((size_t)(N + 1) * sizeof(int));
    int*      cursor = (int*)take((size_t)(N + 1) * sizeof(int));
    int*      bsum   = (int*)take(1024);
    int*      s_src  = (int*)take((size_t)(Etot + 64) * sizeof(int));  // +64 pad
    ushort_t* h1     = (ushort_t*)take((size_t)N * 128 * sizeof(ushort_t));
    ushort_t* xl1b   = (ushort_t*)take((size_t)N * 128 * sizeof(ushort_t));
    ushort_t* xr1b   = (ushort_t*)take((size_t)N * 128 * sizeof(ushort_t));
    ushort_t* xl2b   = (ushort_t*)take((size_t)N * 512 * sizeof(ushort_t));
    ushort_t* xr2b   = (ushort_t*)take((size_t)N * 512 * sizeof(ushort_t));

    dim3 b256(256), b512(512);
    const int nb = (N + 255) / 256;       // 196 scan blocks

    k_detect<<<1, b256, 0, stream>>>((const uint_t*)x, ei, flags);
    hipMemsetAsync(deg, 0, (size_t)N * sizeof(int), stream);
    hipMemsetAsync(s_src + Etot, 0, 64 * sizeof(int), stream);   // pad -> valid row 0

    long prep_total = (long)Etot + (long)N * 16 + 2L * sW1 + 2L * sW2
                    + satt1 + sb1 + satt2 + sb2 + sWo + sbo;
    int prep_blocks = (int)((prep_total + 255) / 256);
    k_prep<<<prep_blocks, b256, 0, stream>>>(x, Wl1, Wr1, att1, b1, Wl2, Wr2, att2, b2, Wo, bo,
                                             ei, E_in, Etot, deg, xb, WTl1, WTr1, WTl2, WTr2,
                                             att1f, b1f, att2f, b2f, Wof, bof,
                                             N, sW1, sW2, satt1, sb1, satt2, sb2, sWo, sbo, flags);

    k_scanA<<<nb, b256, 0, stream>>>(deg, offs, bsum, N);
    k_scanBC<<<nb, b256, 0, stream>>>(offs, cursor, bsum, nb, N);
    k_fill<<<(Etot + 255) / 256, b256, 0, stream>>>(ei, E_in, Etot, flags, cursor, s_src);

    dim3 gg((N / 16 + 7) / 8);
    k_gemm2<128><<<gg, b512, 0, stream>>>(xb, WTl1, WTr1, xl1b, xr1b, N);
    k_l1<<<(N + 3) / 4, b256, 0, stream>>>(xl1b, xr1b, offs, s_src, att1f, b1f, N, h1);

    k_gemm2<512><<<gg, b512, 0, stream>>>(h1, WTl2, WTr2, xl2b, xr2b, N);

    k_l2<<<(N + 3) / 4, b256, 0, stream>>>(xl2b, xr2b, offs, s_src, att2f, b2f, Wof, bof, N, flags, d_out);
}